// Round 7
// baseline (181.542 us; speedup 1.0000x reference)
//
#include <hip/hip_runtime.h>

// ---------------------------------------------------------------------------
// x [2,256,64,64]  y [2,256,32,512]  z [2,128,32,512]  u [2,64,64] int
// wq1/wk1 [128,256,3,3]  wq2/wk2 [128,128,3,3]  biases [128]   out [2,4096,128]
//
// f16 2-term MFMA convs (weights = exact f16 hi+lo split; activations f16).
// Activations halo-padded [B][H+2][IC/32][W+2][32] f16 (zero halos).
// Conv: 32 oc x (2 rows x 128 px | 4 rows x 64 px) blocks, 4 waves,
// wave = 2 rows x 32 px. Weights LDS-staged pre-swizzled (36.9 KB -> 4
// blocks/CU, 16 waves/CU); weight stage reg-prefetched before barrier;
// B-frags double-buffered in registers (next-rs prefetch) from global L2.
// Attention operands (q,k,z) stored f16. 5 launches.
// ---------------------------------------------------------------------------

typedef __attribute__((ext_vector_type(8))) _Float16 f16x8;
typedef __attribute__((ext_vector_type(4))) float f32x4;
typedef __attribute__((ext_vector_type(8))) unsigned short us8;
typedef unsigned short u16;

#define MFMA16F(A, B, C) __builtin_amdgcn_mfma_f32_16x16x32_f16((A), (B), (C), 0, 0, 0)

// Weight layout (pre-swizzled): flat(rs,icb,pl,ocq,j) =
//   rs*(ICB*8192) + icb*8192 + pl*4096 + ocq*1024 + j,
// j = ((ocl*32 + ic) ^ ((ocl&7)<<3)), ocl in [0,32), ic in [0,32).  (bijective)
// Activation layout: FL(b,hp,icb,wp,c) = (((b*H2+hp)*ICB+icb)*W2+wp)*32 + c.

// ---- pack weights (384 blocks) + zero activation halos (127 blocks)
__global__ __launch_bounds__(256) void pack_zero_k(
    const float* __restrict__ wq1, const float* __restrict__ wq2,
    const float* __restrict__ wk1, const float* __restrict__ wk2,
    u16* __restrict__ pq1, u16* __restrict__ pq2,
    u16* __restrict__ pk1, u16* __restrict__ pk2,
    u16* __restrict__ ypad, u16* __restrict__ xpad,
    u16* __restrict__ t2k, u16* __restrict__ t1q)
{
  const int bid = blockIdx.x;
  if (bid < 384) {
    int t = bid * 256 + threadIdx.x;
    const float* w; u16* dst; int IC, tt;
    if (t < 32768)      { w = wq1; dst = pq1; IC = 256; tt = t; }
    else if (t < 49152) { w = wq2; dst = pq2; IC = 128; tt = t - 32768; }
    else if (t < 81920) { w = wk1; dst = pk1; IC = 256; tt = t - 49152; }
    else                { w = wk2; dst = pk2; IC = 128; tt = t - 81920; }
    const int oc = tt / IC, ic = tt % IC;
    const int ICB = IC >> 5;
    const int swz = (((oc & 31) << 5) | (ic & 31)) ^ ((oc & 7) << 3);
    #pragma unroll
    for (int rs = 0; rs < 9; ++rs) {
      float v = w[(oc * IC + ic) * 9 + rs];
      _Float16 hi = (_Float16)v;
      _Float16 lo = (_Float16)(v - (float)hi);
      long base = (long)rs * (ICB * 8192) + (long)(ic >> 5) * 8192
                + (long)(oc >> 5) * 1024 + swz;
      dst[base] = __builtin_bit_cast(u16, hi);
      dst[base + 4096] = __builtin_bit_cast(u16, lo);
    }
  } else {
    // zero halos: units of 32 u16 (64 B). totals: ypad 17472, xpad 4160,
    // t2k 8736, t1q 2080 -> cum 17472, 21632, 30368, 32448.
    long u = (long)(bid - 384) * 256 + threadIdx.x;
    if (u >= 32448) return;
    u16* p; int ICB, H, W2;
    if (u < 17472)      { p = ypad; ICB = 8; H = 32; W2 = 514; }
    else if (u < 21632) { u -= 17472; p = xpad; ICB = 8; H = 64; W2 = 66; }
    else if (u < 30368) { u -= 21632; p = t2k; ICB = 4; H = 32; W2 = 514; }
    else                { u -= 30368; p = t1q; ICB = 4; H = 64; W2 = 66; }
    const int H2 = H + 2;
    const long rowsN = (long)2 * ICB * 2 * W2;
    long base;
    if (u < rowsN) {
      int w = (int)(u % W2);
      int t2 = (int)(u / W2);
      int tb = t2 & 1, icb = (t2 >> 1) % ICB, b = (t2 >> 1) / ICB;
      int h = tb ? H2 - 1 : 0;
      base = ((((long)b * H2 + h) * ICB + icb) * W2 + w) * 32;
    } else {
      long v = u - rowsN;
      int side = (int)(v & 1);
      long v2 = v >> 1;
      int h = 1 + (int)(v2 % H);
      int icb = (int)((v2 / H) % ICB);
      int b = (int)(v2 / ((long)H * ICB));
      int w = side ? W2 - 1 : 0;
      base = ((((long)b * H2 + h) * ICB + icb) * W2 + w) * 32;
    }
    us8 zz = {0, 0, 0, 0, 0, 0, 0, 0};
    #pragma unroll
    for (int j = 0; j < 4; ++j)
      *reinterpret_cast<us8*>(&p[base + j * 8]) = zz;
  }
}

// ---- merged transpose/cvt: y -> ypad f16 [2][34][8][514][32] (interior),
// x -> xpad f16 [2][66][8][66][32], z -> zf16 [2][32][512][128] f16.
__global__ void cvt_all_k(const float* __restrict__ x, const float* __restrict__ y,
                          const float* __restrict__ z,
                          u16* __restrict__ xpad, u16* __restrict__ ypad,
                          u16* __restrict__ zf16)
{
  __shared__ float tile[32][33];
  const int id = blockIdx.x;
  const float* src; int C, H, W, wt, cb, bh, mode, H2, W2;
  u16* d16 = nullptr;
  if (id < 8192)       { src = y; C = 256; H = 32; W = 512; wt = id & 15;       cb = (id >> 4) & 7; bh = id >> 7; d16 = ypad; mode = 0; H2 = 34; W2 = 514; }
  else if (id < 10240) { int i2 = id - 8192;  src = x; C = 256; H = 64; W = 64; wt = i2 & 1;  cb = (i2 >> 1) & 7; bh = i2 >> 4; d16 = xpad; mode = 0; H2 = 66; W2 = 66; }
  else                 { int i3 = id - 10240; src = z; C = 128; H = 32; W = 512; wt = i3 & 15; cb = (i3 >> 4) & 3; bh = i3 >> 6; d16 = zf16; mode = 1; H2 = 0; W2 = 0; }
  const int b = bh / H, h = bh % H;
  const int w0 = wt * 32;
  const int tx = threadIdx.x, ty = threadIdx.y;
  #pragma unroll
  for (int k2 = 0; k2 < 4; ++k2) {
    int c = cb * 32 + ty + k2 * 8;
    tile[ty + k2 * 8][tx] = src[(((long)b * C + c) * H + h) * W + w0 + tx];
  }
  __syncthreads();
  const int j = ty * 32 + tx;
  const int cp = (j & 15) * 2;
  const int wl = j >> 4;
  if (mode == 0) {
    const int ICB = C >> 5;
    #pragma unroll
    for (int half = 0; half < 2; ++half) {
      const int wloc = wl + half * 16;
      unsigned int lo = (unsigned int)__builtin_bit_cast(u16, (_Float16)tile[cp][wloc]);
      unsigned int hi = (unsigned int)__builtin_bit_cast(u16, (_Float16)tile[cp + 1][wloc]);
      long idx = ((((long)b * H2 + h + 1) * ICB + cb) * W2 + (w0 + wloc + 1)) * 32 + cp;
      *reinterpret_cast<unsigned int*>(&d16[idx]) = lo | (hi << 16);
    }
  } else {
    #pragma unroll
    for (int half = 0; half < 2; ++half) {
      const int wloc = wl + half * 16;
      unsigned int lo = (unsigned int)__builtin_bit_cast(u16, (_Float16)tile[cp][wloc]);
      unsigned int hi = (unsigned int)__builtin_bit_cast(u16, (_Float16)tile[cp + 1][wloc]);
      long idx = (((long)b * 32 + h) * 512 + (w0 + wloc)) * 128 + cb * 32 + cp;
      *reinterpret_cast<unsigned int*>(&d16[idx]) = lo | (hi << 16);
    }
  }
}

// ---- merged conv (k blocks [0,512) + q blocks [512,640)).
// Block: 32 oc (ocq) x RPB rows x PXS px; wave = 2 rows x 32 px.
// OF16=1: f16 padded out [B][IH+2][4][IW+2][32] + relu.
// OF16=0: f16 flat out [B][IH][IW][128].
template<int ICB, int OF16>
__global__ __launch_bounds__(256, 4) void conv_k(
    const u16* __restrict__ inK, const u16* __restrict__ wpkK,
    const float* __restrict__ biasK, u16* __restrict__ outK,
    const u16* __restrict__ inQ, const u16* __restrict__ wpkQ,
    const float* __restrict__ biasQ, u16* __restrict__ outQ)
{
  __shared__ __align__(16) u16 smem[18432];   // 36864 B: 9 rs x 2 pl x 1024

  const int tid = threadIdx.x;
  const int lane = tid & 63, wv = tid >> 6;
  const int lm = lane & 15, lq = lane >> 4;
  const int bid = blockIdx.x;

  const u16* in; const u16* wpk; const float* bias; u16* outp;
  int IH, IW, PXS, RPB, wpr, w0, hb, rest;
  if (bid < 512) {
    in = inK; wpk = wpkK; bias = biasK; outp = outK;
    IH = 32; IW = 512; PXS = 128; RPB = 2; wpr = 4;
    w0 = (bid & 3) * 128; hb = ((bid >> 2) & 15) * 2; rest = bid >> 6;
  } else {
    int qb = bid - 512;
    in = inQ; wpk = wpkQ; bias = biasQ; outp = outQ;
    IH = 64; IW = 64; PXS = 64; RPB = 4; wpr = 2;
    w0 = 0; hb = (qb & 15) * 4; rest = qb >> 4;
  }
  const int b = rest >> 2, ocq = rest & 3;
  const int H2 = IH + 2, W2 = IW + 2;
  const int rp = wv / wpr, pxw = (wv % wpr) * 32;
  const int hw0 = hb + rp * 2;

  // A-frag swizzled offsets (mf=0/1); (16+lm)&7 == lm&7 so mf=1 is +512.
  const int aswz0 = (lm * 32 + lq * 8) ^ ((lm & 7) << 3);
  const int aswz1 = aswz0 + 512;

  f32x4 acc[2][2][2];   // [mf][jj][f]
  #pragma unroll
  for (int mf = 0; mf < 2; ++mf)
    #pragma unroll
    for (int jj = 0; jj < 2; ++jj)
      #pragma unroll
      for (int f = 0; f < 2; ++f) acc[mf][jj][f] = (f32x4)0.f;

  for (int icb = 0; icb < ICB; ++icb) {
    // ---- weight-stage reg-prefetch (issued before barrier: latency hides
    // under the barrier wait / other waves' MFMAs)
    uint4 wreg[9];
    #pragma unroll
    for (int j0 = 0; j0 < 9; ++j0) {
      const int off = (j0 * 256 + tid) * 8;
      const int rs2 = off >> 11, pl = (off >> 10) & 1, jj2 = off & 1023;
      wreg[j0] = *reinterpret_cast<const uint4*>(
          wpk + (long)rs2 * (ICB * 8192) + (long)icb * 8192
              + pl * 4096 + ocq * 1024 + jj2);
    }
    // ---- per-lane row base pointers + first B fragment (rs=0) prefetch
    const u16* rb[4];
    #pragma unroll
    for (int jr = 0; jr < 4; ++jr)
      rb[jr] = in + ((((long)b * H2 + hw0 + jr) * ICB + icb) * W2 + (w0 + pxw + lm)) * 32
             + lq * 8;
    f16x8 b0[2][2], b1[2][2];
    #pragma unroll
    for (int jj = 0; jj < 2; ++jj)
      #pragma unroll
      for (int f = 0; f < 2; ++f)
        b0[jj][f] = *reinterpret_cast<const f16x8*>(rb[jj] + (f * 16) * 32);

    __syncthreads();   // prior iter done reading smem
    #pragma unroll
    for (int j0 = 0; j0 < 9; ++j0)
      *reinterpret_cast<uint4*>(&smem[(j0 * 256 + tid) * 8]) = wreg[j0];
    __syncthreads();

    #pragma unroll
    for (int rs = 0; rs < 9; ++rs) {
      const int r = rs / 3, s = rs % 3;
      auto& cur = (rs & 1) ? b1 : b0;
      auto& nxt = (rs & 1) ? b0 : b1;
      if (rs < 8) {   // prefetch next rs's B fragments
        const int r2 = (rs + 1) / 3, s2 = (rs + 1) % 3;
        #pragma unroll
        for (int jj = 0; jj < 2; ++jj)
          #pragma unroll
          for (int f = 0; f < 2; ++f)
            nxt[jj][f] = *reinterpret_cast<const f16x8*>(rb[jj + r2] + (f * 16 + s2) * 32);
      }
      const int tb = rs * 2048;
      const f16x8 a0h = *reinterpret_cast<const f16x8*>(&smem[tb + aswz0]);
      const f16x8 a0l = *reinterpret_cast<const f16x8*>(&smem[tb + 1024 + aswz0]);
      const f16x8 a1h = *reinterpret_cast<const f16x8*>(&smem[tb + aswz1]);
      const f16x8 a1l = *reinterpret_cast<const f16x8*>(&smem[tb + 1024 + aswz1]);
      #pragma unroll
      for (int jj = 0; jj < 2; ++jj)
        #pragma unroll
        for (int f = 0; f < 2; ++f) {
          acc[0][jj][f] = MFMA16F(a0h, cur[jj][f], acc[0][jj][f]);
          acc[0][jj][f] = MFMA16F(a0l, cur[jj][f], acc[0][jj][f]);
          acc[1][jj][f] = MFMA16F(a1h, cur[jj][f], acc[1][jj][f]);
          acc[1][jj][f] = MFMA16F(a1l, cur[jj][f], acc[1][jj][f]);
        }
      (void)r; (void)s;
    }
  }

  // ---- epilogue: bias (+relu for OF16), swizzled LDS staging, f16 write
  __syncthreads();
  u16* st = smem;   // [RPB][PXS][32] u16 (16 KB)
  #pragma unroll
  for (int mf = 0; mf < 2; ++mf)
    #pragma unroll
    for (int jj = 0; jj < 2; ++jj)
      #pragma unroll
      for (int f = 0; f < 2; ++f)
        #pragma unroll
        for (int reg = 0; reg < 4; ++reg) {
          const int ocl = mf * 16 + lq * 4 + reg;
          const int px = pxw + f * 16 + lm;
          const int row = rp * 2 + jj;
          float v = acc[mf][jj][f][reg] + bias[ocq * 32 + ocl];
          if (OF16) v = fmaxf(v, 0.f);
          st[(row * PXS + px) * 32 + (ocl ^ ((px & 3) << 3))] =
              __builtin_bit_cast(u16, (_Float16)v);
        }
  __syncthreads();
  const int tot = RPB * PXS * 4;   // us8 chunks
  for (int i = tid; i < tot; i += 256) {
    const int o8 = i & 3, pxr = i >> 2;
    const int px = pxr % PXS, row = pxr / PXS;
    us8 val = *reinterpret_cast<const us8*>(
        &st[(row * PXS + px) * 32 + ((o8 * 8) ^ ((px & 3) << 3))]);
    u16* dst;
    if (OF16)
      dst = outp + ((((long)b * H2 + hb + row + 1) * 4 + ocq) * W2 + (w0 + px + 1)) * 32
          + o8 * 8;
    else
      dst = outp + (((long)b * IH + hb + row) * IW + w0 + px) * 128 + ocq * 32 + o8 * 8;
    *reinterpret_cast<us8*>(dst) = val;
  }
}

// ---- attention: one block per (b, n). 128 threads. All operands f16.
// q [B,4096,128], k/z [B,32,512,128], u [B,4096] -> out [B,4096,128] f32.
__global__ __launch_bounds__(128) void attn_k(
    const u16* __restrict__ qf, const u16* __restrict__ kf,
    const u16* __restrict__ zf, const int* __restrict__ u,
    float* __restrict__ out)
{
  constexpr float SCALE = 0.08838834764831845f;  // 128^-0.5
  const int n = blockIdx.x, b = blockIdx.y;
  const int t = threadIdx.x;

  __shared__ float qs[128];
  __shared__ float logit[32];
  __shared__ float el[32];

  int widx = u[b * 4096 + n];
  widx = widx < 0 ? 0 : (widx > 511 ? 511 : widx);

  qs[t] = (float)__builtin_bit_cast(_Float16, qf[((long)b * 4096 + n) * 128 + t]);
  __syncthreads();

  const int h = t >> 2, quad = t & 3;
  const u16* kcol = kf + (((long)b * 32 + h) * 512 + widx) * 128 + quad * 32;
  float p = 0.f;
  #pragma unroll
  for (int j = 0; j < 32; j += 8) {
    f16x8 kv = *reinterpret_cast<const f16x8*>(kcol + j);
    #pragma unroll
    for (int jj = 0; jj < 8; ++jj)
      p = fmaf(qs[quad * 32 + j + jj], (float)kv[jj], p);
  }
  p += __shfl_xor(p, 1);
  p += __shfl_xor(p, 2);
  if (quad == 0) logit[h] = p * SCALE;
  __syncthreads();

  float m = -3.4e38f;
  #pragma unroll
  for (int h2 = 0; h2 < 32; ++h2) m = fmaxf(m, logit[h2]);
  if (t < 32) el[t] = __expf(logit[t] - m);
  __syncthreads();
  float den = 0.f;
  #pragma unroll
  for (int h2 = 0; h2 < 32; ++h2) den += el[h2];

  const u16* zcol = zf + ((long)b * 32 * 512) * 128 + (long)widx * 128 + t;
  float o0 = 0.f, o1 = 0.f, o2 = 0.f, o3 = 0.f;
  #pragma unroll
  for (int h2 = 0; h2 < 32; h2 += 4) {
    o0 = fmaf(el[h2 + 0], (float)__builtin_bit_cast(_Float16, zcol[(long)(h2 + 0) * 512 * 128]), o0);
    o1 = fmaf(el[h2 + 1], (float)__builtin_bit_cast(_Float16, zcol[(long)(h2 + 1) * 512 * 128]), o1);
    o2 = fmaf(el[h2 + 2], (float)__builtin_bit_cast(_Float16, zcol[(long)(h2 + 2) * 512 * 128]), o2);
    o3 = fmaf(el[h2 + 3], (float)__builtin_bit_cast(_Float16, zcol[(long)(h2 + 3) * 512 * 128]), o3);
  }
  out[((long)b * 4096 + n) * 128 + t] = ((o0 + o1) + (o2 + o3)) / den;
}

extern "C" void kernel_launch(void* const* d_in, const int* in_sizes, int n_in,
                              void* d_out, int out_size, void* d_ws, size_t ws_size,
                              hipStream_t stream) {
  const float* x   = (const float*)d_in[0];
  const float* y   = (const float*)d_in[1];
  const float* z   = (const float*)d_in[2];
  const int*   u   = (const int*)  d_in[3];
  const float* wq1 = (const float*)d_in[4];
  const float* bq1 = (const float*)d_in[5];
  const float* wq2 = (const float*)d_in[6];
  const float* bq2 = (const float*)d_in[7];
  const float* wk1 = (const float*)d_in[8];
  const float* bk1 = (const float*)d_in[9];
  const float* wk2 = (const float*)d_in[10];
  const float* bk2 = (const float*)d_in[11];
  float* out = (float*)d_out;
  u16* wsu = (u16*)d_ws;

  // ---- arena (u16 offsets); total 56.0 MB
  u16* ypad  = wsu + 0;           //  8,947,712  [2][34][8][514][32] f16
  u16* xpad  = wsu + 8947712;     //  2,230,272  [2][66][8][66][32]  f16
  u16* t2k   = wsu + 11177984;    //  4,473,856  [2][34][4][514][32] f16
  u16* t1q   = wsu + 15651840;    //  1,115,136  [2][66][4][66][32]  f16
  u16* zf16  = wsu + 16766976;    //  4,194,304  [2][32][512][128]   f16
  u16* k_f16 = wsu + 20961280;    //  4,194,304  [2][32][512][128]   f16
  u16* q_f16 = wsu + 25155584;    //  1,048,576  [2,4096,128]        f16
  u16* wpk_q1 = wsu + 26204160;   //    589,824 (hi+lo, pre-swizzled)
  u16* wpk_q2 = wsu + 26793984;   //    294,912
  u16* wpk_k1 = wsu + 27088896;   //    589,824
  u16* wpk_k2 = wsu + 27678720;   //    294,912  -> end 27,973,632 u16

  pack_zero_k<<<dim3(511), 256, 0, stream>>>(wq1, wq2, wk1, wk2,
                                             wpk_q1, wpk_q2, wpk_k1, wpk_k2,
                                             ypad, xpad, t2k, t1q);
  cvt_all_k<<<dim3(14336), dim3(32, 8), 0, stream>>>(x, y, z, xpad, ypad, zf16);
  conv_k<8, 1><<<dim3(640), 256, 0, stream>>>(
      ypad, wpk_k1, bk1, t2k, xpad, wpk_q1, bq1, t1q);
  conv_k<4, 0><<<dim3(640), 256, 0, stream>>>(
      t2k, wpk_k2, bk2, k_f16, t1q, wpk_q2, bq2, q_f16);
  attn_k<<<dim3(4096, 2), 128, 0, stream>>>(q_f16, k_f16, zf16, u, out);
}

// Round 8
// 112.505 us; speedup vs baseline: 1.6136x; 1.6136x over previous
//
#include <hip/hip_runtime.h>

// ---------------------------------------------------------------------------
// x [2,256,64,64]  y [2,256,32,512]  z [2,128,32,512]  u [2,64,64] int
// wq1/wk1 [128,256,3,3]  wq2/wk2 [128,128,3,3]  biases [128]   out [2,4096,128]
//
// Single-plane f16 MFMA convs (weights RN-rounded to f16; activations f16;
// fp32 MFMA accumulation). Activations halo-padded [B][H+2][IC/32][W+2][32]
// f16 (zero halos -> no bounds checks). Conv: 32 oc x (2 rows x 128 px |
// 4 rows x 64 px) blocks, 4 waves, wave = 2 rows x 32 px.
// Weights LDS-staged pre-swizzled (18.4 KB); B-frags per-rs direct from
// global (coalesced 1KB/wave-load, L1/L2-hot). Per rs per wave:
// 2 ds_read_b128 + 4 B-loads + 8 MFMA. 5 launches.
// ---------------------------------------------------------------------------

typedef __attribute__((ext_vector_type(8))) _Float16 f16x8;
typedef __attribute__((ext_vector_type(4))) float f32x4;
typedef __attribute__((ext_vector_type(8))) unsigned short us8;
typedef unsigned short u16;

#define MFMA16F(A, B, C) __builtin_amdgcn_mfma_f32_16x16x32_f16((A), (B), (C), 0, 0, 0)

// Weight layout (pre-swizzled, single plane): flat(rs,icb,ocq,j) =
//   rs*(ICB*4096) + icb*4096 + ocq*1024 + j,
// j = ((ocl*32 + ic) ^ ((ocl&7)<<3)), ocl in [0,32), ic in [0,32). (bijective)
// Activation layout: FL(b,hp,icb,wp,c) = (((b*H2+hp)*ICB+icb)*W2+wp)*32 + c.

// ---- pack weights (384 blocks) + zero activation halos (127 blocks)
__global__ __launch_bounds__(256) void pack_zero_k(
    const float* __restrict__ wq1, const float* __restrict__ wq2,
    const float* __restrict__ wk1, const float* __restrict__ wk2,
    u16* __restrict__ pq1, u16* __restrict__ pq2,
    u16* __restrict__ pk1, u16* __restrict__ pk2,
    u16* __restrict__ ypad, u16* __restrict__ xpad,
    u16* __restrict__ t2k, u16* __restrict__ t1q)
{
  const int bid = blockIdx.x;
  if (bid < 384) {
    int t = bid * 256 + threadIdx.x;
    const float* w; u16* dst; int IC, tt;
    if (t < 32768)      { w = wq1; dst = pq1; IC = 256; tt = t; }
    else if (t < 49152) { w = wq2; dst = pq2; IC = 128; tt = t - 32768; }
    else if (t < 81920) { w = wk1; dst = pk1; IC = 256; tt = t - 49152; }
    else                { w = wk2; dst = pk2; IC = 128; tt = t - 81920; }
    const int oc = tt / IC, ic = tt % IC;
    const int ICB = IC >> 5;
    const int ocl = oc & 31, ocq = oc >> 5;
    const int swz = ((ocl << 5) | (ic & 31)) ^ ((ocl & 7) << 3);
    #pragma unroll
    for (int rs = 0; rs < 9; ++rs) {
      float v = w[(oc * IC + ic) * 9 + rs];
      long base = (long)rs * (ICB * 4096) + (long)(ic >> 5) * 4096
                + (long)ocq * 1024 + swz;
      dst[base] = __builtin_bit_cast(u16, (_Float16)v);
    }
  } else {
    // zero halos: units of 32 u16 (64 B). totals: ypad 17472, xpad 4160,
    // t2k 8736, t1q 2080 -> cum 17472, 21632, 30368, 32448.
    long u = (long)(bid - 384) * 256 + threadIdx.x;
    if (u >= 32448) return;
    u16* p; int ICB, H, W2;
    if (u < 17472)      { p = ypad; ICB = 8; H = 32; W2 = 514; }
    else if (u < 21632) { u -= 17472; p = xpad; ICB = 8; H = 64; W2 = 66; }
    else if (u < 30368) { u -= 21632; p = t2k; ICB = 4; H = 32; W2 = 514; }
    else                { u -= 30368; p = t1q; ICB = 4; H = 64; W2 = 66; }
    const int H2 = H + 2;
    const long rowsN = (long)2 * ICB * 2 * W2;
    long base;
    if (u < rowsN) {
      int w = (int)(u % W2);
      int t2 = (int)(u / W2);
      int tb = t2 & 1, icb = (t2 >> 1) % ICB, b = (t2 >> 1) / ICB;
      int h = tb ? H2 - 1 : 0;
      base = ((((long)b * H2 + h) * ICB + icb) * W2 + w) * 32;
    } else {
      long v = u - rowsN;
      int side = (int)(v & 1);
      long v2 = v >> 1;
      int h = 1 + (int)(v2 % H);
      int icb = (int)((v2 / H) % ICB);
      int b = (int)(v2 / ((long)H * ICB));
      int w = side ? W2 - 1 : 0;
      base = ((((long)b * H2 + h) * ICB + icb) * W2 + w) * 32;
    }
    us8 zz = {0, 0, 0, 0, 0, 0, 0, 0};
    #pragma unroll
    for (int j = 0; j < 4; ++j)
      *reinterpret_cast<us8*>(&p[base + j * 8]) = zz;
  }
}

// ---- merged transpose/cvt: y -> ypad f16 [2][34][8][514][32] (interior),
// x -> xpad f16 [2][66][8][66][32], z -> zf16 [2][32][512][128] f16.
__global__ void cvt_all_k(const float* __restrict__ x, const float* __restrict__ y,
                          const float* __restrict__ z,
                          u16* __restrict__ xpad, u16* __restrict__ ypad,
                          u16* __restrict__ zf16)
{
  __shared__ float tile[32][33];
  const int id = blockIdx.x;
  const float* src; int C, H, W, wt, cb, bh, mode, H2, W2;
  u16* d16 = nullptr;
  if (id < 8192)       { src = y; C = 256; H = 32; W = 512; wt = id & 15;       cb = (id >> 4) & 7; bh = id >> 7; d16 = ypad; mode = 0; H2 = 34; W2 = 514; }
  else if (id < 10240) { int i2 = id - 8192;  src = x; C = 256; H = 64; W = 64; wt = i2 & 1;  cb = (i2 >> 1) & 7; bh = i2 >> 4; d16 = xpad; mode = 0; H2 = 66; W2 = 66; }
  else                 { int i3 = id - 10240; src = z; C = 128; H = 32; W = 512; wt = i3 & 15; cb = (i3 >> 4) & 3; bh = i3 >> 6; d16 = zf16; mode = 1; H2 = 0; W2 = 0; }
  const int b = bh / H, h = bh % H;
  const int w0 = wt * 32;
  const int tx = threadIdx.x, ty = threadIdx.y;
  #pragma unroll
  for (int k2 = 0; k2 < 4; ++k2) {
    int c = cb * 32 + ty + k2 * 8;
    tile[ty + k2 * 8][tx] = src[(((long)b * C + c) * H + h) * W + w0 + tx];
  }
  __syncthreads();
  const int j = ty * 32 + tx;
  const int cp = (j & 15) * 2;
  const int wl = j >> 4;
  if (mode == 0) {
    const int ICB = C >> 5;
    #pragma unroll
    for (int half = 0; half < 2; ++half) {
      const int wloc = wl + half * 16;
      unsigned int lo = (unsigned int)__builtin_bit_cast(u16, (_Float16)tile[cp][wloc]);
      unsigned int hi = (unsigned int)__builtin_bit_cast(u16, (_Float16)tile[cp + 1][wloc]);
      long idx = ((((long)b * H2 + h + 1) * ICB + cb) * W2 + (w0 + wloc + 1)) * 32 + cp;
      *reinterpret_cast<unsigned int*>(&d16[idx]) = lo | (hi << 16);
    }
  } else {
    #pragma unroll
    for (int half = 0; half < 2; ++half) {
      const int wloc = wl + half * 16;
      unsigned int lo = (unsigned int)__builtin_bit_cast(u16, (_Float16)tile[cp][wloc]);
      unsigned int hi = (unsigned int)__builtin_bit_cast(u16, (_Float16)tile[cp + 1][wloc]);
      long idx = (((long)b * 32 + h) * 512 + (w0 + wloc)) * 128 + cb * 32 + cp;
      *reinterpret_cast<unsigned int*>(&d16[idx]) = lo | (hi << 16);
    }
  }
}

// ---- merged conv (k blocks [0,512) + q blocks [512,640)).
// Block: 32 oc (ocq) x RPB rows x PXS px; wave = 2 rows x 32 px.
// OF16=1: f16 padded out [B][IH+2][4][IW+2][32] + relu.
// OF16=0: f16 flat out [B][IH][IW][128].
template<int ICB, int OF16>
__global__ __launch_bounds__(256, 4) void conv_k(
    const u16* __restrict__ inK, const u16* __restrict__ wpkK,
    const float* __restrict__ biasK, u16* __restrict__ outK,
    const u16* __restrict__ inQ, const u16* __restrict__ wpkQ,
    const float* __restrict__ biasQ, u16* __restrict__ outQ)
{
  __shared__ __align__(16) u16 smem[9216];   // 18432 B: 9 rs x 1024 (32oc x 32ic)

  const int tid = threadIdx.x;
  const int lane = tid & 63, wv = tid >> 6;
  const int lm = lane & 15, lq = lane >> 4;
  const int bid = blockIdx.x;

  const u16* in; const u16* wpk; const float* bias; u16* outp;
  int IH, IW, PXS, RPB, wpr, w0, hb, rest;
  if (bid < 512) {
    in = inK; wpk = wpkK; bias = biasK; outp = outK;
    IH = 32; IW = 512; PXS = 128; RPB = 2; wpr = 4;
    w0 = (bid & 3) * 128; hb = ((bid >> 2) & 15) * 2; rest = bid >> 6;
  } else {
    int qb = bid - 512;
    in = inQ; wpk = wpkQ; bias = biasQ; outp = outQ;
    IH = 64; IW = 64; PXS = 64; RPB = 4; wpr = 2;
    w0 = 0; hb = (qb & 15) * 4; rest = qb >> 4;
  }
  const int b = rest >> 2, ocq = rest & 3;
  const int H2 = IH + 2, W2 = IW + 2;
  const int rp = wv / wpr, pxw = (wv % wpr) * 32;
  const int hw0 = hb + rp * 2;

  // A-frag swizzled offsets (mf=0/1); (16+lm)&7 == lm&7 so mf=1 is +512.
  const int aswz0 = (lm * 32 + lq * 8) ^ ((lm & 7) << 3);
  const int aswz1 = aswz0 + 512;

  f32x4 acc[2][2][2];   // [mf][jj][f]
  #pragma unroll
  for (int mf = 0; mf < 2; ++mf)
    #pragma unroll
    for (int jj = 0; jj < 2; ++jj)
      #pragma unroll
      for (int f = 0; f < 2; ++f) acc[mf][jj][f] = (f32x4)0.f;

  for (int icb = 0; icb < ICB; ++icb) {
    __syncthreads();
    // ---- stage this icb's 9 pre-swizzled 32x32 weight tiles (linear copy)
    #pragma unroll
    for (int c0 = 0; c0 < 5; ++c0) {
      const int c = c0 * 256 + tid;
      if (c < 1152) {
        const int rs2 = c >> 7;
        const int j = (c & 127) * 8;
        *reinterpret_cast<uint4*>(&smem[rs2 * 1024 + j]) =
            *reinterpret_cast<const uint4*>(
                wpk + (long)rs2 * (ICB * 4096) + (long)icb * 4096 + ocq * 1024 + j);
      }
    }
    // ---- per-lane row base pointers into padded input
    const u16* rb[4];
    #pragma unroll
    for (int jr = 0; jr < 4; ++jr)
      rb[jr] = in + ((((long)b * H2 + hw0 + jr) * ICB + icb) * W2 + (w0 + pxw + lm)) * 32
             + lq * 8;
    __syncthreads();

    #pragma unroll
    for (int r = 0; r < 3; ++r)
      #pragma unroll
      for (int s = 0; s < 3; ++s) {
        const int rs = r * 3 + s;
        f16x8 bb[2][2];
        #pragma unroll
        for (int jj = 0; jj < 2; ++jj)
          #pragma unroll
          for (int f = 0; f < 2; ++f)
            bb[jj][f] = *reinterpret_cast<const f16x8*>(rb[jj + r] + (f * 16 + s) * 32);
        const int tb = rs * 1024;
        const f16x8 a0 = *reinterpret_cast<const f16x8*>(&smem[tb + aswz0]);
        const f16x8 a1 = *reinterpret_cast<const f16x8*>(&smem[tb + aswz1]);
        #pragma unroll
        for (int jj = 0; jj < 2; ++jj)
          #pragma unroll
          for (int f = 0; f < 2; ++f) {
            acc[0][jj][f] = MFMA16F(a0, bb[jj][f], acc[0][jj][f]);
            acc[1][jj][f] = MFMA16F(a1, bb[jj][f], acc[1][jj][f]);
          }
      }
  }

  // ---- epilogue: bias (+relu for OF16), swizzled LDS staging, f16 write
  __syncthreads();
  u16* st = smem;   // [RPB][PXS][32] u16 (16 KB)
  #pragma unroll
  for (int mf = 0; mf < 2; ++mf)
    #pragma unroll
    for (int jj = 0; jj < 2; ++jj)
      #pragma unroll
      for (int f = 0; f < 2; ++f)
        #pragma unroll
        for (int reg = 0; reg < 4; ++reg) {
          const int ocl = mf * 16 + lq * 4 + reg;
          const int px = pxw + f * 16 + lm;
          const int row = rp * 2 + jj;
          float v = acc[mf][jj][f][reg] + bias[ocq * 32 + ocl];
          if (OF16) v = fmaxf(v, 0.f);
          st[(row * PXS + px) * 32 + (ocl ^ ((px & 3) << 3))] =
              __builtin_bit_cast(u16, (_Float16)v);
        }
  __syncthreads();
  const int tot = RPB * PXS * 4;   // us8 chunks
  for (int i = tid; i < tot; i += 256) {
    const int o8 = i & 3, pxr = i >> 2;
    const int px = pxr % PXS, row = pxr / PXS;
    us8 val = *reinterpret_cast<const us8*>(
        &st[(row * PXS + px) * 32 + ((o8 * 8) ^ ((px & 3) << 3))]);
    u16* dst;
    if (OF16)
      dst = outp + ((((long)b * H2 + hb + row + 1) * 4 + ocq) * W2 + (w0 + px + 1)) * 32
          + o8 * 8;
    else
      dst = outp + (((long)b * IH + hb + row) * IW + w0 + px) * 128 + ocq * 32 + o8 * 8;
    *reinterpret_cast<us8*>(dst) = val;
  }
}

// ---- attention: one block per (b, n). 128 threads. All operands f16.
// q [B,4096,128], k/z [B,32,512,128], u [B,4096] -> out [B,4096,128] f32.
__global__ __launch_bounds__(128) void attn_k(
    const u16* __restrict__ qf, const u16* __restrict__ kf,
    const u16* __restrict__ zf, const int* __restrict__ u,
    float* __restrict__ out)
{
  constexpr float SCALE = 0.08838834764831845f;  // 128^-0.5
  const int n = blockIdx.x, b = blockIdx.y;
  const int t = threadIdx.x;

  __shared__ float qs[128];
  __shared__ float logit[32];
  __shared__ float el[32];

  int widx = u[b * 4096 + n];
  widx = widx < 0 ? 0 : (widx > 511 ? 511 : widx);

  qs[t] = (float)__builtin_bit_cast(_Float16, qf[((long)b * 4096 + n) * 128 + t]);
  __syncthreads();

  const int h = t >> 2, quad = t & 3;
  const u16* kcol = kf + (((long)b * 32 + h) * 512 + widx) * 128 + quad * 32;
  float p = 0.f;
  #pragma unroll
  for (int j = 0; j < 32; j += 8) {
    f16x8 kv = *reinterpret_cast<const f16x8*>(kcol + j);
    #pragma unroll
    for (int jj = 0; jj < 8; ++jj)
      p = fmaf(qs[quad * 32 + j + jj], (float)kv[jj], p);
  }
  p += __shfl_xor(p, 1);
  p += __shfl_xor(p, 2);
  if (quad == 0) logit[h] = p * SCALE;
  __syncthreads();

  float m = -3.4e38f;
  #pragma unroll
  for (int h2 = 0; h2 < 32; ++h2) m = fmaxf(m, logit[h2]);
  if (t < 32) el[t] = __expf(logit[t] - m);
  __syncthreads();
  float den = 0.f;
  #pragma unroll
  for (int h2 = 0; h2 < 32; ++h2) den += el[h2];

  const u16* zcol = zf + ((long)b * 32 * 512) * 128 + (long)widx * 128 + t;
  float o0 = 0.f, o1 = 0.f, o2 = 0.f, o3 = 0.f;
  #pragma unroll
  for (int h2 = 0; h2 < 32; h2 += 4) {
    o0 = fmaf(el[h2 + 0], (float)__builtin_bit_cast(_Float16, zcol[(long)(h2 + 0) * 512 * 128]), o0);
    o1 = fmaf(el[h2 + 1], (float)__builtin_bit_cast(_Float16, zcol[(long)(h2 + 1) * 512 * 128]), o1);
    o2 = fmaf(el[h2 + 2], (float)__builtin_bit_cast(_Float16, zcol[(long)(h2 + 2) * 512 * 128]), o2);
    o3 = fmaf(el[h2 + 3], (float)__builtin_bit_cast(_Float16, zcol[(long)(h2 + 3) * 512 * 128]), o3);
  }
  out[((long)b * 4096 + n) * 128 + t] = ((o0 + o1) + (o2 + o3)) / den;
}

extern "C" void kernel_launch(void* const* d_in, const int* in_sizes, int n_in,
                              void* d_out, int out_size, void* d_ws, size_t ws_size,
                              hipStream_t stream) {
  const float* x   = (const float*)d_in[0];
  const float* y   = (const float*)d_in[1];
  const float* z   = (const float*)d_in[2];
  const int*   u   = (const int*)  d_in[3];
  const float* wq1 = (const float*)d_in[4];
  const float* bq1 = (const float*)d_in[5];
  const float* wq2 = (const float*)d_in[6];
  const float* bq2 = (const float*)d_in[7];
  const float* wk1 = (const float*)d_in[8];
  const float* bk1 = (const float*)d_in[9];
  const float* wk2 = (const float*)d_in[10];
  const float* bk2 = (const float*)d_in[11];
  float* out = (float*)d_out;
  u16* wsu = (u16*)d_ws;

  // ---- arena (u16 offsets); total 54.2 MB
  u16* ypad  = wsu + 0;           //  8,947,712  [2][34][8][514][32] f16
  u16* xpad  = wsu + 8947712;     //  2,230,272  [2][66][8][66][32]  f16
  u16* t2k   = wsu + 11177984;    //  4,473,856  [2][34][4][514][32] f16
  u16* t1q   = wsu + 15651840;    //  1,115,136  [2][66][4][66][32]  f16
  u16* zf16  = wsu + 16766976;    //  4,194,304  [2][32][512][128]   f16
  u16* k_f16 = wsu + 20961280;    //  4,194,304  [2][32][512][128]   f16
  u16* q_f16 = wsu + 25155584;    //  1,048,576  [2,4096,128]        f16
  u16* wpk_q1 = wsu + 26204160;   //    294,912  (single plane, pre-swizzled)
  u16* wpk_q2 = wsu + 26499072;   //    147,456
  u16* wpk_k1 = wsu + 26646528;   //    294,912
  u16* wpk_k2 = wsu + 26941440;   //    147,456  -> end 27,088,896 u16

  pack_zero_k<<<dim3(511), 256, 0, stream>>>(wq1, wq2, wk1, wk2,
                                             wpk_q1, wpk_q2, wpk_k1, wpk_k2,
                                             ypad, xpad, t2k, t1q);
  cvt_all_k<<<dim3(14336), dim3(32, 8), 0, stream>>>(x, y, z, xpad, ypad, zf16);
  conv_k<8, 1><<<dim3(640), 256, 0, stream>>>(
      ypad, wpk_k1, bk1, t2k, xpad, wpk_q1, bq1, t1q);
  conv_k<4, 0><<<dim3(640), 256, 0, stream>>>(
      t2k, wpk_k2, bk2, k_f16, t1q, wpk_q2, bq2, q_f16);
  attn_k<<<dim3(4096, 2), 128, 0, stream>>>(q_f16, k_f16, zf16, u, out);
}